// Round 4
// baseline (668.873 us; speedup 1.0000x reference)
//
#include <hip/hip_runtime.h>
#include <stdint.h>

#define NB  64
#define SEQ 2048
#define DIM 512
#define NS  (NB*SEQ)   // 131072 flattened s-rows

typedef __bf16 bf16x8 __attribute__((ext_vector_type(8)));
typedef float  f32x4  __attribute__((ext_vector_type(4)));
typedef unsigned int u32;
typedef unsigned short u16;
typedef unsigned int u32x4 __attribute__((ext_vector_type(4)));

// pack two fp32 -> two bf16 (round-half-up; same numerics as verified kernel)
__device__ __forceinline__ u32 pk_bf16(float a, float b){
  union {float f; u32 i;} x, y; x.f = a; y.f = b;
  return ((x.i + 0x8000u) >> 16) | ((y.i + 0x8000u) & 0xffff0000u);
}
// tanh(x) = 1 - 2/(e^{2x}+1)
__device__ __forceinline__ float fast_tanh(float x){
  float e = __builtin_amdgcn_exp2f(x * 2.885390081777927f);  // 2*log2(e)
  return 1.0f - 2.0f*__builtin_amdgcn_rcpf(e + 1.0f);
}

// ---------------- kernel 0: Wr_w fp32 -> bf16 fragment-image ---------------
// cell i in [0,32768): eb=i>>10, kt=(i>>6)&15, quad=(i>>4)&3, col=i&15.
// cell holds Wr_w[e = eb*16+col][k = kt*32+quad*8 .. +7] as 8 bf16 (16 B).
// A wave's B-fragment load for (eb,kt) reads 64 lanes x 16 B CONTIGUOUS.
__global__ void wconv_kernel(const float* __restrict__ Wr_w, u16* __restrict__ wrbf)
{
  const int i = blockIdx.x*256 + threadIdx.x;        // 32768 cells
  const int eb = i >> 10, kt = (i >> 6) & 15, quad = (i >> 4) & 3, col = i & 15;
  const float* g = Wr_w + (size_t)(eb*16 + col)*DIM + kt*32 + quad*8;
  f32x4 a = *(const f32x4*)g, c = *(const f32x4*)(g + 4);
  u32x4 p;
  p[0]=pk_bf16(a.x,a.y); p[1]=pk_bf16(a.z,a.w);
  p[2]=pk_bf16(c.x,c.y); p[3]=pk_bf16(c.z,c.w);
  ((u32x4*)wrbf)[i] = p;
}

// ---------------- kernel 1: q = query @ Wq_w^T + Wq_b (fp32 into ws) --------
__global__ void q_kernel(const float* __restrict__ query, const float* __restrict__ Wq_w,
                         const float* __restrict__ Wq_b, float* __restrict__ qws)
{
  __shared__ float lq[DIM];
  const int b   = blockIdx.x;
  const int tid = threadIdx.x;           // 256
  const int e   = blockIdx.y*256 + tid;  // 0..511
  for (int i = tid; i < DIM; i += 256) lq[i] = query[b*DIM + i];
  __syncthreads();
  const float* wr = Wq_w + (size_t)e*DIM;
  float acc = 0.f;
  for (int d = 0; d < DIM; d += 4){
    f32x4 w = *(const f32x4*)(wr + d);
    acc += w.x*lq[d] + w.y*lq[d+1] + w.z*lq[d+2] + w.w*lq[d+3];
  }
  qws[b*DIM + e] = acc + Wq_b[e];
}

// ---------------- kernel 2: persistent, cross-tile pipelined ----------------
// 256 blocks x 512 threads, 1 block/CU (LDS 132 KB). Block owns 8 consecutive
// 64-row s-tiles (all in one batch). Ref LDS double-buffered: tile t+1 staging
// (issue kt0/kt8, pack+write kt4-5/12-13) overlaps tile t's k-loop; epilogue
// stores drain under the next tile. 8 waves split e (64 each) -> logits done
// in-block, one barrier per tile. W stream is periodic mod 16 kt (L2-resident).
__global__ __launch_bounds__(512, 2)
void main_kernel(const float* __restrict__ ref,  const u16* __restrict__ wrbf,
                 const float* __restrict__ Wr_b, const float* __restrict__ value,
                 const float* __restrict__ qws,  float* __restrict__ out)
{
  __shared__ __align__(16) char smem[135168];      // 2x64KB ref + 4KB lred
  float* lred = (float*)(smem + 131072);           // [2][8][64]

  const int tid  = threadIdx.x;                    // 512
  const int lane = tid & 63, wave = tid >> 6;      // 8 waves
  const int col  = lane & 15, quad = lane >> 4;

  const int t0 = blockIdx.x * 8;                   // tiles t0..t0+7
  const int b  = t0 >> 5;                          // same batch for all 8 tiles

  // epilogue constants: wave's e-slice, e = wave*64 + mi*16 + col
  float bb[4], qq[4], vv[4];
#pragma unroll
  for (int mi = 0; mi < 4; ++mi){
    const int e = wave*64 + mi*16 + col;
    bb[mi] = Wr_b[e]; qq[mi] = qws[b*DIM + e]; vv[mi] = value[e];
  }

  // W fragment: eb = wave*4 + mi, contiguous 1 KB per (eb,kt)
  auto wptr = [&](int kt, int mi){
    return (const bf16x8*)(wrbf + ((size_t)((wave*4 + mi)*1024 + kt*64 + lane))*8);
  };

  // ---- prologue: stage tile 0 into buffer 0 ------------------------------
  {
    const float* src = ref + ((size_t)t0*64 + wave)*DIM + lane*8;
#pragma unroll
    for (int j = 0; j < 8; ++j){
      const float* g = src + (size_t)j*8*DIM;      // row = j*8 + wave
      f32x4 x0 = *(const f32x4*)g, x1 = *(const f32x4*)(g+4);
      u32x4 p;
      p[0]=pk_bf16(x0.x,x0.y); p[1]=pk_bf16(x0.z,x0.w);
      p[2]=pk_bf16(x1.x,x1.y); p[3]=pk_bf16(x1.z,x1.w);
      *(u32x4*)(smem + (j*8+wave)*1024 + (lane^wave)*16) = p;
    }
  }
  bf16x8 wb[2][4];
#pragma unroll
  for (int mi = 0; mi < 4; ++mi) wb[0][mi] = *wptr(0, mi);
  __syncthreads();

  bf16x8 rbuf[2][4];
#pragma unroll
  for (int ni = 0; ni < 4; ++ni){
    const int r = ni*16 + col;
    rbuf[0][ni] = *(const bf16x8*)(smem + r*1024 + ((quad ^ (col&7)))*16);
  }

  f32x4 sx[4][2];                                  // staging in-flight regs

#pragma unroll 1
  for (int i = 0; i < 8; ++i){
    char* curL = smem + ((i & 1) << 16);
    char* nxtL = smem + (((i & 1) ^ 1) << 16);
    const bool st = (i < 7);
    const int sb = ((t0 + i) & 31) * 64;
    const float* nsrc = ref + ((size_t)(t0+i+1)*64 + wave)*DIM + lane*8;

    f32x4 acc[4][4];
#pragma unroll
    for (int mi = 0; mi < 4; ++mi)
#pragma unroll
      for (int ni = 0; ni < 4; ++ni) acc[mi][ni] = (f32x4)0.0f;
    float ls[4][4];
#pragma unroll
    for (int ni = 0; ni < 4; ++ni)
#pragma unroll
      for (int rg = 0; rg < 4; ++rg) ls[ni][rg] = 0.f;

#pragma unroll
    for (int kt = 0; kt < 16; ++kt){
      // W prefetch, 1 kt ahead (periodic mod 16: kt15 preloads next tile's kt0)
#pragma unroll
      for (int mi = 0; mi < 4; ++mi) wb[(kt+1)&1][mi] = *wptr((kt+1)&15, mi);

      // staging of tile i+1: issue-early / write-late (T14)
      if (st && kt == 0){
#pragma unroll
        for (int j = 0; j < 4; ++j){
          const float* g = nsrc + (size_t)j*8*DIM;
          sx[j][0] = *(const f32x4*)g; sx[j][1] = *(const f32x4*)(g+4);
        }
      }
      if (st && (kt == 4 || kt == 5)){
#pragma unroll
        for (int jj = 0; jj < 2; ++jj){
          const int j = (kt-4)*2 + jj;
          u32x4 p;
          p[0]=pk_bf16(sx[j][0].x,sx[j][0].y); p[1]=pk_bf16(sx[j][0].z,sx[j][0].w);
          p[2]=pk_bf16(sx[j][1].x,sx[j][1].y); p[3]=pk_bf16(sx[j][1].z,sx[j][1].w);
          *(u32x4*)(nxtL + (j*8+wave)*1024 + (lane^wave)*16) = p;
        }
      }
      if (st && kt == 8){
#pragma unroll
        for (int j = 0; j < 4; ++j){
          const float* g = nsrc + (size_t)(j+4)*8*DIM;
          sx[j][0] = *(const f32x4*)g; sx[j][1] = *(const f32x4*)(g+4);
        }
      }
      if (st && (kt == 12 || kt == 13)){
#pragma unroll
        for (int jj = 0; jj < 2; ++jj){
          const int j = (kt-12)*2 + jj;
          u32x4 p;
          p[0]=pk_bf16(sx[j][0].x,sx[j][0].y); p[1]=pk_bf16(sx[j][0].z,sx[j][0].w);
          p[2]=pk_bf16(sx[j][1].x,sx[j][1].y); p[3]=pk_bf16(sx[j][1].z,sx[j][1].w);
          *(u32x4*)(nxtL + ((j+4)*8+wave)*1024 + (lane^wave)*16) = p;
        }
      }

      // ref fragment prefetch, 1 kt ahead (same buffer); kt15's successor is
      // loaded post-barrier from the other buffer
      if (kt < 15){
#pragma unroll
        for (int ni = 0; ni < 4; ++ni){
          const int r = ni*16 + col;
          rbuf[(kt+1)&1][ni] = *(const bf16x8*)(curL + r*1024 + ((((kt+1)*4+quad) ^ (col&7)))*16);
        }
      }

      // 16 MFMA: D[s][e], A = ref frag (s rows), B = W frag (e cols)
#pragma unroll
      for (int mi = 0; mi < 4; ++mi)
#pragma unroll
        for (int ni = 0; ni < 4; ++ni)
          acc[mi][ni] = __builtin_amdgcn_mfma_f32_16x16x32_bf16(
              rbuf[kt&1][ni], wb[kt&1][mi], acc[mi][ni], 0, 0, 0);
    }

    // ---- epilogue: bias + coalesced stores + fused logits ------------------
#pragma unroll
    for (int mi = 0; mi < 4; ++mi){
      const int e = wave*64 + mi*16 + col;
      float* orow = out + ((size_t)(b*DIM + e))*SEQ + sb + quad*4;
#pragma unroll
      for (int ni = 0; ni < 4; ++ni){    // s = sb + ni*16 + quad*4 + rg
        f32x4 v = acc[mi][ni];
        v.x += bb[mi]; v.y += bb[mi]; v.z += bb[mi]; v.w += bb[mi];
        *(f32x4*)(orow + ni*16) = v;
        ls[ni][0] += fast_tanh(qq[mi] + v.x) * vv[mi];
        ls[ni][1] += fast_tanh(qq[mi] + v.y) * vv[mi];
        ls[ni][2] += fast_tanh(qq[mi] + v.z) * vv[mi];
        ls[ni][3] += fast_tanh(qq[mi] + v.w) * vv[mi];
      }
    }

    // logits: reduce over col (e within wave), then across waves via LDS
#pragma unroll
    for (int ni = 0; ni < 4; ++ni)
#pragma unroll
      for (int rg = 0; rg < 4; ++rg){
        float x = ls[ni][rg];
        x += __shfl_xor(x, 1); x += __shfl_xor(x, 2);
        x += __shfl_xor(x, 4); x += __shfl_xor(x, 8);
        ls[ni][rg] = x;
      }
    float* lr = lred + (i & 1) * 512;
    if (col == 0){
#pragma unroll
      for (int ni = 0; ni < 4; ++ni)
#pragma unroll
        for (int rg = 0; rg < 4; ++rg)
          lr[wave*64 + ni*16 + quad*4 + rg] = ls[ni][rg];
    }
    __syncthreads();                     // staging writes + lred visible
    if (tid < 64){
      float s = 0.f;
#pragma unroll
      for (int w = 0; w < 8; ++w) s += lr[w*64 + tid];
      out[(size_t)NB*DIM*SEQ + (size_t)b*SEQ + sb + tid] = 10.0f * fast_tanh(s);
    }
    if (st){                             // next tile's kt0 ref frags
#pragma unroll
      for (int ni = 0; ni < 4; ++ni){
        const int r = ni*16 + col;
        rbuf[0][ni] = *(const bf16x8*)(nxtL + r*1024 + ((quad ^ (col&7)))*16);
      }
    }
  }
}

extern "C" void kernel_launch(void* const* d_in, const int* in_sizes, int n_in,
                              void* d_out, int out_size, void* d_ws, size_t ws_size,
                              hipStream_t stream)
{
  const float* query = (const float*)d_in[0];
  const float* ref   = (const float*)d_in[1];
  const float* Wq_w  = (const float*)d_in[2];
  const float* Wq_b  = (const float*)d_in[3];
  const float* Wr_w  = (const float*)d_in[4];
  const float* Wr_b  = (const float*)d_in[5];
  const float* value = (const float*)d_in[6];
  float* out = (float*)d_out;

  float* qws  = (float*)d_ws;                       // 64*512 fp32 = 128 KB
  u16*   wrbf = (u16*)((float*)d_ws + NB*DIM);      // 512*512 bf16 = 512 KB

  wconv_kernel<<<dim3(128), dim3(256), 0, stream>>>(Wr_w, wrbf);
  q_kernel<<<dim3(NB, 2), dim3(256), 0, stream>>>(query, Wq_w, Wq_b, qws);
  main_kernel<<<dim3(256), dim3(512), 0, stream>>>(ref, wrbf, Wr_b, value, qws, out);
}

// Round 5
// 534.491 us; speedup vs baseline: 1.2514x; 1.2514x over previous
//
#include <hip/hip_runtime.h>
#include <stdint.h>

#define NB  64
#define SEQ 2048
#define DIM 512
#define NS  (NB*SEQ)   // 131072 flattened s-rows

typedef __bf16 bf16x8 __attribute__((ext_vector_type(8)));
typedef float  f32x4  __attribute__((ext_vector_type(4)));
typedef unsigned int u32;
typedef unsigned short u16;
typedef unsigned int u32x4 __attribute__((ext_vector_type(4)));

// pack two fp32 -> two bf16 (round-half-up; same numerics as verified kernel)
__device__ __forceinline__ u32 pk_bf16(float a, float b){
  union {float f; u32 i;} x, y; x.f = a; y.f = b;
  return ((x.i + 0x8000u) >> 16) | ((y.i + 0x8000u) & 0xffff0000u);
}
// tanh(x) = 1 - 2/(e^{2x}+1)
__device__ __forceinline__ float fast_tanh(float x){
  float e = __builtin_amdgcn_exp2f(x * 2.885390081777927f);  // 2*log2(e)
  return 1.0f - 2.0f*__builtin_amdgcn_rcpf(e + 1.0f);
}

// ---------------- kernel 0: Wr_w fp32 -> bf16 fragment-image ---------------
// cell i in [0,32768): eb=i>>10, kt=(i>>6)&15, quad=(i>>4)&3, col=i&15.
// cell holds Wr_w[e = eb*16+col][k = kt*32+quad*8 .. +7] as 8 bf16 (16 B).
// A wave's B-fragment load for (eb,kt) reads 64 lanes x 16 B CONTIGUOUS.
__global__ void wconv_kernel(const float* __restrict__ Wr_w, u16* __restrict__ wrbf)
{
  const int i = blockIdx.x*256 + threadIdx.x;        // 32768 cells
  const int eb = i >> 10, kt = (i >> 6) & 15, quad = (i >> 4) & 3, col = i & 15;
  const float* g = Wr_w + (size_t)(eb*16 + col)*DIM + kt*32 + quad*8;
  f32x4 a = *(const f32x4*)g, c = *(const f32x4*)(g + 4);
  u32x4 p;
  p[0]=pk_bf16(a.x,a.y); p[1]=pk_bf16(a.z,a.w);
  p[2]=pk_bf16(c.x,c.y); p[3]=pk_bf16(c.z,c.w);
  ((u32x4*)wrbf)[i] = p;
}

// ---------------- kernel 1: q = query @ Wq_w^T + Wq_b (fp32 into ws) --------
__global__ void q_kernel(const float* __restrict__ query, const float* __restrict__ Wq_w,
                         const float* __restrict__ Wq_b, float* __restrict__ qws)
{
  __shared__ float lq[DIM];
  const int b   = blockIdx.x;
  const int tid = threadIdx.x;           // 256
  const int e   = blockIdx.y*256 + tid;  // 0..511
  for (int i = tid; i < DIM; i += 256) lq[i] = query[b*DIM + i];
  __syncthreads();
  const float* wr = Wq_w + (size_t)e*DIM;
  float acc = 0.f;
  for (int d = 0; d < DIM; d += 4){
    f32x4 w = *(const f32x4*)(wr + d);
    acc += w.x*lq[d] + w.y*lq[d+1] + w.z*lq[d+2] + w.w*lq[d+3];
  }
  qws[b*DIM + e] = acc + Wq_b[e];
}

// ---------------- kernel 2: one block = 32 s-rows x ALL 512 e ---------------
// Round-3 free-running structure at DOUBLE occupancy: 4096 blocks x 512 thr
// (8 waves), 33 KB LDS -> 2 blocks/CU = 16 waves/CU (4 waves/SIMD of TLP).
// ref tile staged ONCE (bf16, swizzled LDS); W streamed from L2-resident
// fragment image straight to registers (3-slot ring, 2-kt lookahead); zero
// barriers in k-loop; fused epilogue; logits complete in-block.
__global__ __launch_bounds__(512, 4)
void main_kernel(const float* __restrict__ ref,  const u16* __restrict__ wrbf,
                 const float* __restrict__ Wr_b, const float* __restrict__ value,
                 const float* __restrict__ qws,  float* __restrict__ out)
{
  __shared__ __align__(16) char smem[33792];
  float* lred = (float*)(smem + 32768);    // [8][32]

  const int tid  = threadIdx.x;            // 512
  const int lane = tid & 63, wave = tid >> 6;
  const int col  = lane & 15, quad = lane >> 4;
  const size_t s0 = (size_t)blockIdx.x * 32;
  const int b  = (int)(s0 >> 11);          // 2048 % 32 == 0: tile within one batch
  const int sb = (int)(s0 & 2047);

  // epilogue constants: wave's 64-e slice, e = wave*64 + mi*16 + col
  float bb[4], qq[4], vv[4];
#pragma unroll
  for (int mi = 0; mi < 4; ++mi){
    const int e = wave*64 + mi*16 + col;
    bb[mi] = Wr_b[e]; qq[mi] = qws[b*DIM + e]; vv[mi] = value[e];
  }

  // W fragment: eb = wave*4 + mi, contiguous 1 KB per (eb,kt)
  auto wptr = [&](int kt, int mi){
    return (const bf16x8*)(wrbf + ((size_t)(((wave*4 + mi)*16 + kt)*64 + lane))*8);
  };

  bf16x8 wb[3][4];                         // ring kt%3, 2-kt lookahead
#pragma unroll
  for (int mi = 0; mi < 4; ++mi) wb[0][mi] = *wptr(0, mi);
#pragma unroll
  for (int mi = 0; mi < 4; ++mi) wb[1][mi] = *wptr(1, mi);

  // ---- stage ref tile -> bf16 swizzled LDS (W loads in flight above) ------
#pragma unroll
  for (int it = 0; it < 4; ++it){
    const int c   = it*512 + tid;          // 2048 16B-chunks: [32 rows][64 chunks]
    const int row = c >> 6, ch = c & 63;
    const float* g = ref + (s0 + row)*DIM + ch*8;
    f32x4 x0 = *(const f32x4*)g, x1 = *(const f32x4*)(g+4);
    u32x4 p;
    p[0]=pk_bf16(x0.x,x0.y); p[1]=pk_bf16(x0.z,x0.w);
    p[2]=pk_bf16(x1.x,x1.y); p[3]=pk_bf16(x1.z,x1.w);
    *(u32x4*)(smem + row*1024 + (ch ^ (row&7))*16) = p;
  }
  __syncthreads();

  bf16x8 rbuf[2][2];                       // ref frags, 1-kt lookahead
#pragma unroll
  for (int ni = 0; ni < 2; ++ni){
    const int r = ni*16 + col;
    rbuf[0][ni] = *(const bf16x8*)(smem + r*1024 + ((quad ^ (r&7)))*16);
  }

  f32x4 acc[4][2];                         // [mi][ni]
#pragma unroll
  for (int mi = 0; mi < 4; ++mi)
#pragma unroll
    for (int ni = 0; ni < 2; ++ni) acc[mi][ni] = (f32x4)0.0f;

#pragma unroll
  for (int kt = 0; kt < 16; ++kt){
    if (kt + 2 < 16){                      // W prefetch, 2 kt ahead
#pragma unroll
      for (int mi = 0; mi < 4; ++mi) wb[(kt+2)%3][mi] = *wptr(kt+2, mi);
    }
    if (kt < 15){                          // ref prefetch, 1 kt ahead
#pragma unroll
      for (int ni = 0; ni < 2; ++ni){
        const int r = ni*16 + col;
        rbuf[(kt+1)&1][ni] = *(const bf16x8*)(smem + r*1024 + ((((kt+1)*4+quad) ^ (r&7)))*16);
      }
    }
#pragma unroll
    for (int mi = 0; mi < 4; ++mi)
#pragma unroll
      for (int ni = 0; ni < 2; ++ni)       // D[s][e]: A = ref frag, B = W frag
        acc[mi][ni] = __builtin_amdgcn_mfma_f32_16x16x32_bf16(
            rbuf[kt&1][ni], wb[kt%3][mi], acc[mi][ni], 0, 0, 0);
  }

  // ---- epilogue: bias + coalesced f32x4 stores + fused logits --------------
  float ls[2][4];
#pragma unroll
  for (int ni = 0; ni < 2; ++ni)
#pragma unroll
    for (int rg = 0; rg < 4; ++rg) ls[ni][rg] = 0.f;

#pragma unroll
  for (int mi = 0; mi < 4; ++mi){
    const int e = wave*64 + mi*16 + col;
    float* orow = out + ((size_t)(b*DIM + e))*SEQ + sb + quad*4;
#pragma unroll
    for (int ni = 0; ni < 2; ++ni){        // s = sb + ni*16 + quad*4 + rg
      f32x4 v = acc[mi][ni];
      v.x += bb[mi]; v.y += bb[mi]; v.z += bb[mi]; v.w += bb[mi];
      *(f32x4*)(orow + ni*16) = v;
      ls[ni][0] += fast_tanh(qq[mi] + v.x) * vv[mi];
      ls[ni][1] += fast_tanh(qq[mi] + v.y) * vv[mi];
      ls[ni][2] += fast_tanh(qq[mi] + v.z) * vv[mi];
      ls[ni][3] += fast_tanh(qq[mi] + v.w) * vv[mi];
    }
  }

  // logits: reduce over col (16 e-lanes), then across 8 waves via LDS
#pragma unroll
  for (int ni = 0; ni < 2; ++ni)
#pragma unroll
    for (int rg = 0; rg < 4; ++rg){
      float x = ls[ni][rg];
      x += __shfl_xor(x, 1); x += __shfl_xor(x, 2);
      x += __shfl_xor(x, 4); x += __shfl_xor(x, 8);
      ls[ni][rg] = x;
    }
  if (col == 0){
#pragma unroll
    for (int ni = 0; ni < 2; ++ni)
#pragma unroll
      for (int rg = 0; rg < 4; ++rg)
        lred[wave*32 + ni*16 + quad*4 + rg] = ls[ni][rg];
  }
  __syncthreads();
  if (tid < 32){
    float s = 0.f;
#pragma unroll
    for (int w = 0; w < 8; ++w) s += lred[w*32 + tid];
    out[(size_t)NB*DIM*SEQ + (size_t)b*SEQ + sb + tid] = 10.0f * fast_tanh(s);
  }
}

extern "C" void kernel_launch(void* const* d_in, const int* in_sizes, int n_in,
                              void* d_out, int out_size, void* d_ws, size_t ws_size,
                              hipStream_t stream)
{
  const float* query = (const float*)d_in[0];
  const float* ref   = (const float*)d_in[1];
  const float* Wq_w  = (const float*)d_in[2];
  const float* Wq_b  = (const float*)d_in[3];
  const float* Wr_w  = (const float*)d_in[4];
  const float* Wr_b  = (const float*)d_in[5];
  const float* value = (const float*)d_in[6];
  float* out = (float*)d_out;

  float* qws  = (float*)d_ws;                       // 64*512 fp32 = 128 KB
  u16*   wrbf = (u16*)((float*)d_ws + NB*DIM);      // 512*512 bf16 = 512 KB

  wconv_kernel<<<dim3(128), dim3(256), 0, stream>>>(Wr_w, wrbf);
  q_kernel<<<dim3(NB, 2), dim3(256), 0, stream>>>(query, Wq_w, Wq_b, qws);
  main_kernel<<<dim3(NS/32), dim3(512), 0, stream>>>(ref, wrbf, Wr_b, value, qws, out);
}